// Round 10
// baseline (444.675 us; speedup 1.0000x reference)
//
#include <hip/hip_runtime.h>
#include <hip/hip_bf16.h>
#include <math.h>

#define N_NODES 50000
#define N_EDGES 800000
#define ETOT    850000   // E + N self-loops
#define IN_DIM  256
#define HC      256      // HEADS*CD
#define HEADS   4
#define CD      64

typedef __bf16    bf16x8 __attribute__((ext_vector_type(8)));
typedef float     f32x4  __attribute__((ext_vector_type(4)));
typedef _Float16  f16x4  __attribute__((ext_vector_type(4)));

static __device__ __forceinline__ float lrelu(float x) { return x > 0.f ? x : 0.2f * x; }

static __device__ __forceinline__ unsigned short bf16_rne(float f) {
    union { float f; unsigned u; } c; c.f = f;
    unsigned u = c.u;
    return (unsigned short)((u + 0x7FFFu + ((u >> 16) & 1u)) >> 16);
}
static __device__ __forceinline__ float bf16_to_f(unsigned short h) {
    union { unsigned u; float f; } c; c.u = ((unsigned)h) << 16;
    return c.f;
}

// ---------------- CSR build ----------------
__global__ void k_init(int* counts, int* cursor) {
    int i = blockIdx.x * 256 + threadIdx.x;
    if (i < N_NODES) { counts[i] = 1; cursor[i] = 0; }   // 1 = self loop
}

__global__ void k_degree(const int* __restrict__ dst, int* __restrict__ counts) {
    int i = blockIdx.x * 256 + threadIdx.x;
    if (i < N_EDGES) atomicAdd(&counts[dst[i]], 1);
}

__global__ __launch_bounds__(1024) void k_scan_a(const int* __restrict__ counts,
                                                 int* __restrict__ rowptr,
                                                 int* __restrict__ bsum) {
    __shared__ int sd[1024];
    int t = threadIdx.x;
    int i = blockIdx.x * 1024 + t;
    int v = (i < N_NODES) ? counts[i] : 0;
    sd[t] = v; __syncthreads();
    for (int off = 1; off < 1024; off <<= 1) {
        int add = (t >= off) ? sd[t - off] : 0;
        __syncthreads();
        sd[t] += add;
        __syncthreads();
    }
    if (i < N_NODES) rowptr[i + 1] = sd[t];
    if (t == 1023) bsum[blockIdx.x] = sd[1023];
    if (i == 0) rowptr[0] = 0;
}

__global__ void k_scan_b(int* bsum, int nb) {
    if (threadIdx.x == 0) {
        int run = 0;
        for (int b = 0; b < nb; ++b) { int t = bsum[b]; bsum[b] = run; run += t; }
    }
}

__global__ void k_scan_c(int* __restrict__ rowptr, const int* __restrict__ bsum) {
    int i = blockIdx.x * 256 + threadIdx.x;
    if (i < N_NODES) rowptr[i + 1] += bsum[i >> 10];
}

__global__ void k_scatter(const int* __restrict__ src, const int* __restrict__ dst,
                          const int* __restrict__ rowptr, int* __restrict__ cursor,
                          int* __restrict__ src_sorted) {
    int i = blockIdx.x * 256 + threadIdx.x;
    if (i >= ETOT) return;
    int s, d;
    if (i < N_EDGES) { s = src[i]; d = dst[i]; }
    else             { s = i - N_EDGES; d = s; }
    int pos = rowptr[d] + atomicAdd(&cursor[d], 1);
    src_sorted[pos] = s;
}

// ---------------- split-bf16 conversion ----------------
__global__ void k_convx(const float* __restrict__ x,
                        unsigned short* __restrict__ hi,
                        unsigned short* __restrict__ lo) {
    int i = blockIdx.x * 256 + threadIdx.x;                // indexes float4
    if (i >= N_NODES * IN_DIM / 4) return;
    float4 v = reinterpret_cast<const float4*>(x)[i];
    ushort4 h, l;
    h.x = bf16_rne(v.x); l.x = bf16_rne(v.x - bf16_to_f(h.x));
    h.y = bf16_rne(v.y); l.y = bf16_rne(v.y - bf16_to_f(h.y));
    h.z = bf16_rne(v.z); l.z = bf16_rne(v.z - bf16_to_f(h.z));
    h.w = bf16_rne(v.w); l.w = bf16_rne(v.w - bf16_to_f(h.w));
    reinterpret_cast<ushort4*>(hi)[i] = h;
    reinterpret_cast<ushort4*>(lo)[i] = l;
}

// W[K=256][Nc] f32 -> WT[Nc][256] bf16 hi/lo
__global__ void k_convw(const float* __restrict__ W,
                        unsigned short* __restrict__ hiT,
                        unsigned short* __restrict__ loT, int Nc) {
    int idx = blockIdx.x * 256 + threadIdx.x;
    if (idx >= Nc * 256) return;
    int n = idx >> 8, k = idx & 255;
    float v = W[(size_t)k * Nc + n];
    unsigned short h = bf16_rne(v);
    hiT[idx] = h;
    loT[idx] = bf16_rne(v - bf16_to_f(h));
}

// ---------------- register-fragment split-bf16 MFMA GEMM, fused logit epilogue ----
// No LDS, no barriers. Wave tile = 32 rows x 64 cols (acc 2x4 f32x4 = 32 VGPR).
// Layer1 (Nc=256): block = 4 waves on the SAME 32 rows, wave w = col-block w
//   -> A fragments identical across waves (L1 broadcast). grid (1, ceil(M/32)).
// Layer2 (Nc=64): block = 4 waves stacking 4 row-slabs (128 rows). grid (1, ceil(M/128)).
// Epilogue: fp16 store + complete per-row logit dot (wave owns full head) -> plain store.
__global__ __launch_bounds__(256) void k_gemm_r(
    const unsigned short* __restrict__ Ahi, const unsigned short* __restrict__ Alo,
    const unsigned short* __restrict__ BThi, const unsigned short* __restrict__ BTlo,
    _Float16* __restrict__ Of16,
    float* __restrict__ s_out, float* __restrict__ d_out,
    const float* __restrict__ a_s, const float* __restrict__ a_d,
    int M, int Nc)
{
    const int lane = threadIdx.x & 63, w = threadIdx.x >> 6;
    const int nCB = Nc >> 6;                    // col-blocks total: 4 (layer1) or 1 (layer2)
    const int lg  = (nCB == 4) ? 2 : 0;
    const int cb  = w & (nCB - 1);              // this wave's col-block
    const int rs  = w >> lg;                    // this wave's row-slab within block
    const int row0 = blockIdx.y * (128 >> lg) + rs * 32;
    const int col0 = cb * 64;
    const int rl = lane & 15, kg = lane >> 4;   // fragment lane-row, k-group

    f32x4 acc[2][4];
    const f32x4 fzero = {0.f, 0.f, 0.f, 0.f};
    #pragma unroll
    for (int m = 0; m < 2; ++m)
        #pragma unroll
        for (int n = 0; n < 4; ++n) acc[m][n] = fzero;

    // per-lane element offsets (A row / B col fragment bases)
    size_t aoff[2], boff[4];
    #pragma unroll
    for (int m = 0; m < 2; ++m) {
        int r = row0 + m * 16 + rl; if (r >= M) r = M - 1;
        aoff[m] = (size_t)r * 256 + kg * 8;
    }
    #pragma unroll
    for (int n = 0; n < 4; ++n) {
        int c = col0 + n * 16 + rl;
        boff[n] = (size_t)c * 256 + kg * 8;
    }

    #pragma unroll
    for (int k0 = 0; k0 < 256; k0 += 32) {
        bf16x8 ah[2], al[2], bh[4], bl[4];
        #pragma unroll
        for (int m = 0; m < 2; ++m) {
            ah[m] = *reinterpret_cast<const bf16x8*>(Ahi + aoff[m] + k0);
            al[m] = *reinterpret_cast<const bf16x8*>(Alo + aoff[m] + k0);
        }
        #pragma unroll
        for (int n = 0; n < 4; ++n) {
            bh[n] = *reinterpret_cast<const bf16x8*>(BThi + boff[n] + k0);
            bl[n] = *reinterpret_cast<const bf16x8*>(BTlo + boff[n] + k0);
        }
        #pragma unroll
        for (int m = 0; m < 2; ++m)
            #pragma unroll
            for (int n = 0; n < 4; ++n) {
                acc[m][n] = __builtin_amdgcn_mfma_f32_16x16x32_bf16(ah[m], bh[n], acc[m][n], 0, 0, 0);
                acc[m][n] = __builtin_amdgcn_mfma_f32_16x16x32_bf16(ah[m], bl[n], acc[m][n], 0, 0, 0);
                acc[m][n] = __builtin_amdgcn_mfma_f32_16x16x32_bf16(al[m], bh[n], acc[m][n], 0, 0, 0);
            }
    }

    // epilogue: C lane map col=(lane&15)+n*16, row=m*16+(lane>>4)*4+r
    const int hs = Nc >> 6;
    float as_[4], ad_[4];
    #pragma unroll
    for (int n = 0; n < 4; ++n) {
        as_[n] = a_s[col0 + n * 16 + rl];
        ad_[n] = a_d[col0 + n * 16 + rl];
    }
    #pragma unroll
    for (int m = 0; m < 2; ++m) {
        #pragma unroll
        for (int r = 0; r < 4; ++r) {
            int row = row0 + m * 16 + kg * 4 + r;
            float v0 = acc[m][0][r], v1 = acc[m][1][r], v2 = acc[m][2][r], v3 = acc[m][3][r];
            float sp = v0 * as_[0] + v1 * as_[1] + v2 * as_[2] + v3 * as_[3];
            float dp = v0 * ad_[0] + v1 * ad_[1] + v2 * ad_[2] + v3 * ad_[3];
            #pragma unroll
            for (int off = 1; off < 16; off <<= 1) {
                sp += __shfl_xor(sp, off, 64);
                dp += __shfl_xor(dp, off, 64);
            }
            if (row < M) {
                _Float16* o = Of16 + (size_t)row * Nc + col0 + rl;
                o[0]  = (_Float16)v0;
                o[16] = (_Float16)v1;
                o[32] = (_Float16)v2;
                o[48] = (_Float16)v3;
                if (rl == 0) {   // complete head sum: unique writer per (row, head)
                    s_out[(size_t)row * hs + cb] = sp;
                    d_out[(size_t)row * hs + cb] = dp;
                }
            }
        }
    }
}

// ---------------- layer-1 softmax+aggregate: one wave per node, fp16 gather ------
// Output written directly as split-bf16 (feeds MFMA GEMM2).
__global__ __launch_bounds__(256) void k_agg1(const int* __restrict__ rowptr,
                                              const int* __restrict__ srcs,
                                              const _Float16* __restrict__ h1f,
                                              const float* __restrict__ s1,
                                              const float* __restrict__ d1,
                                              const float* __restrict__ b1,
                                              unsigned short* __restrict__ o_hi,
                                              unsigned short* __restrict__ o_lo) {
    const int w = threadIdx.x >> 6, l = threadIdx.x & 63;
    const int v = blockIdx.x * 4 + w;
    if (v >= N_NODES) return;
    __shared__ float exs[4][64][4];
    __shared__ int   us[4][64];
    const int row0 = rowptr[v], row1 = rowptr[v + 1];
    const float4 dv = *reinterpret_cast<const float4*>(d1 + 4 * v);
    const int head = l >> 4;               // lane l covers dims [4l,4l+4) -> head l>>4
    float a0 = 0.f, a1 = 0.f, a2 = 0.f, a3 = 0.f, den = 0.f;

    for (int c0 = row0; c0 < row1; c0 += 64) {
        const int nc = min(64, row1 - c0);
        if (l < nc) {
            int u = srcs[c0 + l];
            float4 s = *reinterpret_cast<const float4*>(s1 + 4 * u);
            us[w][l] = u;
            exs[w][l][0] = __expf(lrelu(s.x + dv.x));
            exs[w][l][1] = __expf(lrelu(s.y + dv.y));
            exs[w][l][2] = __expf(lrelu(s.z + dv.z));
            exs[w][l][3] = __expf(lrelu(s.w + dv.w));
        }
        __builtin_amdgcn_wave_barrier();
        for (int j = 0; j < nc; ++j) {
            int u = us[w][j];
            float ex = exs[w][j][head];
            f16x4 hv = *reinterpret_cast<const f16x4*>(h1f + (size_t)u * 256 + l * 4);
            a0 += ex * (float)hv[0];
            a1 += ex * (float)hv[1];
            a2 += ex * (float)hv[2];
            a3 += ex * (float)hv[3];
            den += ex;
        }
        __builtin_amdgcn_wave_barrier();
    }
    const float4 bb = *reinterpret_cast<const float4*>(b1 + l * 4);
    float o0 = fmaxf(a0 / den + bb.x, 0.f);
    float o1 = fmaxf(a1 / den + bb.y, 0.f);
    float o2 = fmaxf(a2 / den + bb.z, 0.f);
    float o3 = fmaxf(a3 / den + bb.w, 0.f);
    ushort4 h4, l4;
    h4.x = bf16_rne(o0); l4.x = bf16_rne(o0 - bf16_to_f(h4.x));
    h4.y = bf16_rne(o1); l4.y = bf16_rne(o1 - bf16_to_f(h4.y));
    h4.z = bf16_rne(o2); l4.z = bf16_rne(o2 - bf16_to_f(h4.z));
    h4.w = bf16_rne(o3); l4.w = bf16_rne(o3 - bf16_to_f(h4.w));
    *reinterpret_cast<ushort4*>(o_hi + (size_t)v * 256 + l * 4) = h4;
    *reinterpret_cast<ushort4*>(o_lo + (size_t)v * 256 + l * 4) = l4;
}

// ---------------- layer-2 softmax+aggregate: one wave per node, fp16 gather ------
__global__ __launch_bounds__(256) void k_agg2(const int* __restrict__ rowptr,
                                              const int* __restrict__ srcs,
                                              const _Float16* __restrict__ t2f,
                                              const float* __restrict__ s2,
                                              const float* __restrict__ d2,
                                              const float* __restrict__ b2,
                                              float* __restrict__ h2) {
    const int w = threadIdx.x >> 6, l = threadIdx.x & 63;
    const int v = blockIdx.x * 4 + w;
    if (v >= N_NODES) return;
    __shared__ float exw[4][64];
    __shared__ int   uw[4][64];
    const int row0 = rowptr[v], row1 = rowptr[v + 1];
    const float dvv = d2[v];
    float acc = 0.f, den = 0.f;
    for (int c0 = row0; c0 < row1; c0 += 64) {
        int nc = min(64, row1 - c0);
        if (l < nc) {
            int u = srcs[c0 + l];
            uw[w][l] = u;
            exw[w][l] = __expf(lrelu(s2[u] + dvv));
        }
        __builtin_amdgcn_wave_barrier();
        for (int j = 0; j < nc; ++j) {
            int u = uw[w][j];
            float ex = exw[w][j];
            acc += ex * (float)t2f[(size_t)u * CD + l];
            den += ex;
        }
        __builtin_amdgcn_wave_barrier();
    }
    h2[(size_t)v * CD + l] = fmaxf(acc / den + b2[l], 0.f);
}

// ---------------- head: entity sigmoid + pooling logits ----------------
__global__ __launch_bounds__(256) void k_head(const float* __restrict__ h2,
                                              const float* __restrict__ att_w,
                                              const float* __restrict__ att_b,
                                              const float* __restrict__ fc_w,
                                              const float* __restrict__ fc_b,
                                              float* __restrict__ logit,
                                              float* __restrict__ outp) {
    int wave = threadIdx.x >> 6, lane = threadIdx.x & 63;
    int v = blockIdx.x * 4 + wave;
    if (v >= N_NODES) return;
    float hv = h2[(size_t)v * CD + lane];
    float a = hv * att_w[lane];
    float f = hv * fc_w[lane];
    #pragma unroll
    for (int off = 32; off; off >>= 1) {
        a += __shfl_down(a, off, 64);
        f += __shfl_down(f, off, 64);
    }
    if (lane == 0) {
        logit[v] = a + att_b[0];
        float z = f + fc_b[0];
        outp[v] = 1.f / (1.f + __expf(-z));
    }
}

// ---------------- global softmax pooling ----------------
__global__ __launch_bounds__(256) void k_pmax(const float* __restrict__ logit,
                                              float* __restrict__ pmax) {
    __shared__ float sd[256];
    int t = threadIdx.x;
    float lm = -1e30f;
    for (int i = blockIdx.x * 256 + t; i < N_NODES; i += gridDim.x * 256)
        lm = fmaxf(lm, logit[i]);
    sd[t] = lm; __syncthreads();
    for (int s = 128; s; s >>= 1) { if (t < s) sd[t] = fmaxf(sd[t], sd[t + s]); __syncthreads(); }
    if (t == 0) pmax[blockIdx.x] = sd[0];
}

__global__ __launch_bounds__(256) void k_finmax(const float* __restrict__ pmax,
                                                float* __restrict__ gmax,
                                                float* __restrict__ gsum,
                                                float* __restrict__ gvec) {
    __shared__ float sd[256];
    int t = threadIdx.x;
    sd[t] = pmax[t];
    __syncthreads();
    for (int s = 128; s; s >>= 1) { if (t < s) sd[t] = fmaxf(sd[t], sd[t + s]); __syncthreads(); }
    if (t == 0) { *gmax = sd[0]; *gsum = 0.f; }
    if (t < 64) gvec[t] = 0.f;
}

__global__ __launch_bounds__(256) void k_pool(const float* __restrict__ h2,
                                              const float* __restrict__ logit,
                                              const float* __restrict__ gmax,
                                              float* __restrict__ gsum,
                                              float* __restrict__ gvec) {
    int wave = threadIdx.x >> 6, lane = threadIdx.x & 63;
    __shared__ float acc_s[4][64];
    __shared__ float ws_s[4];
    float m = *gmax;
    float acc = 0.f, wsum = 0.f;
    int gw = blockIdx.x * 4 + wave;
    int nw = gridDim.x * 4;
    for (int v = gw; v < N_NODES; v += nw) {
        float w = __expf(logit[v] - m);
        acc += w * h2[(size_t)v * CD + lane];
        if (lane == 0) wsum += w;
    }
    acc_s[wave][lane] = acc;
    if (lane == 0) ws_s[wave] = wsum;
    __syncthreads();
    if (threadIdx.x < 64) {
        float a = acc_s[0][threadIdx.x] + acc_s[1][threadIdx.x] +
                  acc_s[2][threadIdx.x] + acc_s[3][threadIdx.x];
        atomicAdd(&gvec[threadIdx.x], a);
    }
    if (threadIdx.x == 0)
        atomicAdd(gsum, ws_s[0] + ws_s[1] + ws_s[2] + ws_s[3]);
}

__global__ void k_writeout(const float* __restrict__ gvec,
                           const float* __restrict__ gsum,
                           float* __restrict__ outg) {
    int t = threadIdx.x;
    if (t < 64) outg[t] = gvec[t] / *gsum;
}

// ---------------- launcher ----------------
extern "C" void kernel_launch(void* const* d_in, const int* in_sizes, int n_in,
                              void* d_out, int out_size, void* d_ws, size_t ws_size,
                              hipStream_t stream) {
    const float* x    = (const float*)d_in[0];
    const int*   ei   = (const int*)d_in[1];
    const float* W1   = (const float*)d_in[2];
    const float* as1  = (const float*)d_in[3];
    const float* ad1  = (const float*)d_in[4];
    const float* b1   = (const float*)d_in[5];
    const float* W2   = (const float*)d_in[6];
    const float* as2  = (const float*)d_in[7];
    const float* ad2  = (const float*)d_in[8];
    const float* b2   = (const float*)d_in[9];
    const float* attw = (const float*)d_in[10];
    const float* attb = (const float*)d_in[11];
    const float* fcw  = (const float*)d_in[12];
    const float* fcb  = (const float*)d_in[13];
    const int* srcE = ei;
    const int* dstE = ei + N_EDGES;

    char* ws = (char*)d_ws;
    size_t off = 0;
    auto take = [&](size_t bytes) -> void* {
        void* p = ws + off;
        off += (bytes + 255) & ~(size_t)255;
        return p;
    };
    _Float16* h1f  = (_Float16*)take((size_t)N_NODES * HC * 2);
    _Float16* t2f  = (_Float16*)take((size_t)N_NODES * CD * 2);
    float* h2   = (float*)take((size_t)N_NODES * CD * 4);
    float* s1   = (float*)take((size_t)N_NODES * 4 * 4);
    float* d1   = (float*)take((size_t)N_NODES * 4 * 4);
    float* s2   = (float*)take((size_t)N_NODES * 4);
    float* d2   = (float*)take((size_t)N_NODES * 4);
    int* counts = (int*)take((size_t)N_NODES * 4);
    int* cursor = (int*)take((size_t)N_NODES * 4);
    int* rowptr = (int*)take((size_t)(N_NODES + 1) * 4);
    int* bsum   = (int*)take(64 * 4);
    int* src_sorted = (int*)take((size_t)ETOT * 4);
    unsigned short* xhi = (unsigned short*)take((size_t)N_NODES * IN_DIM * 2);  // alias: out1hi
    unsigned short* xlo = (unsigned short*)take((size_t)N_NODES * IN_DIM * 2);  // alias: out1lo
    unsigned short* W1Thi = (unsigned short*)take(256 * 256 * 2);
    unsigned short* W1Tlo = (unsigned short*)take(256 * 256 * 2);
    unsigned short* W2Thi = (unsigned short*)take(64 * 256 * 2);
    unsigned short* W2Tlo = (unsigned short*)take(64 * 256 * 2);
    float* logit = (float*)take((size_t)N_NODES * 4);
    float* pmax  = (float*)take(256 * 4);
    float* gmax  = (float*)take(4);
    float* gsum  = (float*)take(4);
    float* gvec  = (float*)take(64 * 4);
    // region reuse (stream-ordered, safe): agg1 writes out1 after gemm1 consumed x
    unsigned short* out1hi = xhi;
    unsigned short* out1lo = xlo;

    // CSR build
    k_init<<<(N_NODES + 255) / 256, 256, 0, stream>>>(counts, cursor);
    k_degree<<<(N_EDGES + 255) / 256, 256, 0, stream>>>(dstE, counts);
    int nb = (N_NODES + 1023) / 1024;
    k_scan_a<<<nb, 1024, 0, stream>>>(counts, rowptr, bsum);
    k_scan_b<<<1, 64, 0, stream>>>(bsum, nb);
    k_scan_c<<<(N_NODES + 255) / 256, 256, 0, stream>>>(rowptr, bsum);
    k_scatter<<<(ETOT + 255) / 256, 256, 0, stream>>>(srcE, dstE, rowptr, cursor, src_sorted);

    // split-bf16 conversions
    k_convx<<<(N_NODES * IN_DIM / 4 + 255) / 256, 256, 0, stream>>>(x, xhi, xlo);
    k_convw<<<(256 * 256 + 255) / 256, 256, 0, stream>>>(W1, W1Thi, W1Tlo, HC);
    k_convw<<<(64 * 256 + 255) / 256, 256, 0, stream>>>(W2, W2Thi, W2Tlo, CD);

    // layer 1: register-fragment GEMM + fused logits -> h1f (fp16), s1, d1
    k_gemm_r<<<dim3(1, (N_NODES + 31) / 32), 256, 0, stream>>>(
        xhi, xlo, W1Thi, W1Tlo, h1f, s1, d1, as1, ad1, N_NODES, HC);
    k_agg1<<<(N_NODES + 3) / 4, 256, 0, stream>>>(rowptr, src_sorted, h1f, s1, d1, b1, out1hi, out1lo);

    // layer 2: register-fragment GEMM + fused logits -> t2f (fp16), s2, d2
    k_gemm_r<<<dim3(1, (N_NODES + 127) / 128), 256, 0, stream>>>(
        out1hi, out1lo, W2Thi, W2Tlo, t2f, s2, d2, as2, ad2, N_NODES, CD);
    k_agg2<<<(N_NODES + 3) / 4, 256, 0, stream>>>(rowptr, src_sorted, t2f, s2, d2, b2, h2);

    // heads
    k_head<<<(N_NODES + 3) / 4, 256, 0, stream>>>(h2, attw, attb, fcw, fcb, logit, (float*)d_out);
    k_pmax<<<256, 256, 0, stream>>>(logit, pmax);
    k_finmax<<<1, 256, 0, stream>>>(pmax, gmax, gsum, gvec);
    k_pool<<<256, 256, 0, stream>>>(h2, logit, gmax, gsum, gvec);
    k_writeout<<<1, 64, 0, stream>>>(gvec, gsum, (float*)d_out + N_NODES);
}

// Round 11
// 386.566 us; speedup vs baseline: 1.1503x; 1.1503x over previous
//
#include <hip/hip_runtime.h>
#include <hip/hip_bf16.h>
#include <math.h>

#define N_NODES 50000
#define N_EDGES 800000
#define ETOT    850000   // E + N self-loops
#define IN_DIM  256
#define HC      256      // HEADS*CD
#define HEADS   4
#define CD      64

typedef _Float16  f16x8 __attribute__((ext_vector_type(8)));
typedef _Float16  f16x4 __attribute__((ext_vector_type(4)));
typedef float     f32x4 __attribute__((ext_vector_type(4)));

static __device__ __forceinline__ float lrelu(float x) { return x > 0.f ? x : 0.2f * x; }

// ---------------- CSR build ----------------
__global__ void k_init(int* counts, int* cursor) {
    int i = blockIdx.x * 256 + threadIdx.x;
    if (i < N_NODES) { counts[i] = 1; cursor[i] = 0; }   // 1 = self loop
}

__global__ void k_degree(const int* __restrict__ dst, int* __restrict__ counts) {
    int i = blockIdx.x * 256 + threadIdx.x;
    if (i < N_EDGES) atomicAdd(&counts[dst[i]], 1);
}

__global__ __launch_bounds__(1024) void k_scan_a(const int* __restrict__ counts,
                                                 int* __restrict__ rowptr,
                                                 int* __restrict__ bsum) {
    __shared__ int sd[1024];
    int t = threadIdx.x;
    int i = blockIdx.x * 1024 + t;
    int v = (i < N_NODES) ? counts[i] : 0;
    sd[t] = v; __syncthreads();
    for (int off = 1; off < 1024; off <<= 1) {
        int add = (t >= off) ? sd[t - off] : 0;
        __syncthreads();
        sd[t] += add;
        __syncthreads();
    }
    if (i < N_NODES) rowptr[i + 1] = sd[t];
    if (t == 1023) bsum[blockIdx.x] = sd[1023];
    if (i == 0) rowptr[0] = 0;
}

__global__ void k_scan_b(int* bsum, int nb) {
    if (threadIdx.x == 0) {
        int run = 0;
        for (int b = 0; b < nb; ++b) { int t = bsum[b]; bsum[b] = run; run += t; }
    }
}

__global__ void k_scan_c(int* __restrict__ rowptr, const int* __restrict__ bsum) {
    int i = blockIdx.x * 256 + threadIdx.x;
    if (i < N_NODES) rowptr[i + 1] += bsum[i >> 10];
}

__global__ void k_scatter(const int* __restrict__ src, const int* __restrict__ dst,
                          const int* __restrict__ rowptr, int* __restrict__ cursor,
                          int* __restrict__ src_sorted) {
    int i = blockIdx.x * 256 + threadIdx.x;
    if (i >= ETOT) return;
    int s, d;
    if (i < N_EDGES) { s = src[i]; d = dst[i]; }
    else             { s = i - N_EDGES; d = s; }
    int pos = rowptr[d] + atomicAdd(&cursor[d], 1);
    src_sorted[pos] = s;
}

// ---------------- fp16 conversions ----------------
__global__ void k_convx16(const float* __restrict__ x, _Float16* __restrict__ o) {
    int i = blockIdx.x * 256 + threadIdx.x;                // indexes float4
    if (i >= N_NODES * IN_DIM / 4) return;
    float4 v = reinterpret_cast<const float4*>(x)[i];
    f16x4 h = {(_Float16)v.x, (_Float16)v.y, (_Float16)v.z, (_Float16)v.w};
    reinterpret_cast<f16x4*>(o)[i] = h;
}

// W[K=256][Nc] f32 -> WT[Nc][256] fp16
__global__ void k_convw16(const float* __restrict__ W, _Float16* __restrict__ oT, int Nc) {
    int idx = blockIdx.x * 256 + threadIdx.x;
    if (idx >= Nc * 256) return;
    int n = idx >> 8, k = idx & 255;
    oT[idx] = (_Float16)W[(size_t)k * Nc + n];
}

// ---------------- fp16 register-fragment MFMA GEMM, fused logit epilogue ----------
// No LDS, no barriers. Wave tile = 64x64 (acc 4x4 f32x4); block = 4 waves = 256 rows.
// A fp16 row-major [M][256]; B transposed [Nc][256] fp16 (L2-resident).
// blockIdx.x = col-block = head. Epilogue: fp16 store + complete per-row logit dot.
__global__ __launch_bounds__(256) void k_gemm_h(
    const _Float16* __restrict__ A, const _Float16* __restrict__ BT,
    _Float16* __restrict__ O,
    float* __restrict__ s_out, float* __restrict__ d_out,
    const float* __restrict__ a_s, const float* __restrict__ a_d,
    int M, int Nc)
{
    const int lane = threadIdx.x & 63, w = threadIdx.x >> 6;
    const int row0 = blockIdx.y * 256 + w * 64;
    const int col0 = blockIdx.x * 64;
    const int hs = Nc >> 6;              // head-slot count (4 layer1, 1 layer2)
    const int rl = lane & 15, kg = lane >> 4;   // fragment lane-row, k-group

    f32x4 acc[4][4];
    const f32x4 fzero = {0.f, 0.f, 0.f, 0.f};
    #pragma unroll
    for (int m = 0; m < 4; ++m)
        #pragma unroll
        for (int n = 0; n < 4; ++n) acc[m][n] = fzero;

    size_t aoff[4], boff[4];
    #pragma unroll
    for (int m = 0; m < 4; ++m) {
        int r = row0 + m * 16 + rl; if (r >= M) r = M - 1;
        aoff[m] = (size_t)r * 256 + kg * 8;
    }
    #pragma unroll
    for (int n = 0; n < 4; ++n) {
        int c = col0 + n * 16 + rl;
        boff[n] = (size_t)c * 256 + kg * 8;
    }

    #pragma unroll 2
    for (int k0 = 0; k0 < 256; k0 += 32) {
        f16x8 a_[4], b_[4];
        #pragma unroll
        for (int m = 0; m < 4; ++m)
            a_[m] = *reinterpret_cast<const f16x8*>(A + aoff[m] + k0);
        #pragma unroll
        for (int n = 0; n < 4; ++n)
            b_[n] = *reinterpret_cast<const f16x8*>(BT + boff[n] + k0);
        #pragma unroll
        for (int m = 0; m < 4; ++m)
            #pragma unroll
            for (int n = 0; n < 4; ++n)
                acc[m][n] = __builtin_amdgcn_mfma_f32_16x16x32_f16(a_[m], b_[n], acc[m][n], 0, 0, 0);
    }

    // epilogue: C lane map col=(lane&15)+n*16, row=m*16+(lane>>4)*4+r
    float as_[4], ad_[4];
    #pragma unroll
    for (int n = 0; n < 4; ++n) {
        as_[n] = a_s[col0 + n * 16 + rl];
        ad_[n] = a_d[col0 + n * 16 + rl];
    }
    #pragma unroll
    for (int m = 0; m < 4; ++m) {
        #pragma unroll
        for (int r = 0; r < 4; ++r) {
            int row = row0 + m * 16 + kg * 4 + r;
            float v0 = acc[m][0][r], v1 = acc[m][1][r], v2 = acc[m][2][r], v3 = acc[m][3][r];
            float sp = v0 * as_[0] + v1 * as_[1] + v2 * as_[2] + v3 * as_[3];
            float dp = v0 * ad_[0] + v1 * ad_[1] + v2 * ad_[2] + v3 * ad_[3];
            #pragma unroll
            for (int off = 1; off < 16; off <<= 1) {
                sp += __shfl_xor(sp, off, 64);
                dp += __shfl_xor(dp, off, 64);
            }
            if (row < M) {
                _Float16* o = O + (size_t)row * Nc + col0 + rl;
                o[0]  = (_Float16)v0;
                o[16] = (_Float16)v1;
                o[32] = (_Float16)v2;
                o[48] = (_Float16)v3;
                if (rl == 0) {   // complete head sum: unique writer per (row, head)
                    s_out[(size_t)row * hs + blockIdx.x] = sp;
                    d_out[(size_t)row * hs + blockIdx.x] = dp;
                }
            }
        }
    }
}

// ---------------- layer-1 softmax+aggregate: one wave per node, fp16 gather ------
// Output written as fp16 (feeds fp16 MFMA GEMM2).
__global__ __launch_bounds__(256) void k_agg1(const int* __restrict__ rowptr,
                                              const int* __restrict__ srcs,
                                              const _Float16* __restrict__ h1f,
                                              const float* __restrict__ s1,
                                              const float* __restrict__ d1,
                                              const float* __restrict__ b1,
                                              _Float16* __restrict__ o_f16) {
    const int w = threadIdx.x >> 6, l = threadIdx.x & 63;
    const int v = blockIdx.x * 4 + w;
    if (v >= N_NODES) return;
    __shared__ float exs[4][64][4];
    __shared__ int   us[4][64];
    const int row0 = rowptr[v], row1 = rowptr[v + 1];
    const float4 dv = *reinterpret_cast<const float4*>(d1 + 4 * v);
    const int head = l >> 4;               // lane l covers dims [4l,4l+4) -> head l>>4
    float a0 = 0.f, a1 = 0.f, a2 = 0.f, a3 = 0.f, den = 0.f;

    for (int c0 = row0; c0 < row1; c0 += 64) {
        const int nc = min(64, row1 - c0);
        if (l < nc) {
            int u = srcs[c0 + l];
            float4 s = *reinterpret_cast<const float4*>(s1 + 4 * u);
            us[w][l] = u;
            exs[w][l][0] = __expf(lrelu(s.x + dv.x));
            exs[w][l][1] = __expf(lrelu(s.y + dv.y));
            exs[w][l][2] = __expf(lrelu(s.z + dv.z));
            exs[w][l][3] = __expf(lrelu(s.w + dv.w));
        }
        __builtin_amdgcn_wave_barrier();
        for (int j = 0; j < nc; ++j) {
            int u = us[w][j];
            float ex = exs[w][j][head];
            f16x4 hv = *reinterpret_cast<const f16x4*>(h1f + (size_t)u * 256 + l * 4);
            a0 += ex * (float)hv[0];
            a1 += ex * (float)hv[1];
            a2 += ex * (float)hv[2];
            a3 += ex * (float)hv[3];
            den += ex;
        }
        __builtin_amdgcn_wave_barrier();
    }
    const float4 bb = *reinterpret_cast<const float4*>(b1 + l * 4);
    f16x4 o4;
    o4[0] = (_Float16)fmaxf(a0 / den + bb.x, 0.f);
    o4[1] = (_Float16)fmaxf(a1 / den + bb.y, 0.f);
    o4[2] = (_Float16)fmaxf(a2 / den + bb.z, 0.f);
    o4[3] = (_Float16)fmaxf(a3 / den + bb.w, 0.f);
    *reinterpret_cast<f16x4*>(o_f16 + (size_t)v * 256 + l * 4) = o4;
}

// ---------------- layer-2 softmax+aggregate: one wave per node, fp16 gather ------
__global__ __launch_bounds__(256) void k_agg2(const int* __restrict__ rowptr,
                                              const int* __restrict__ srcs,
                                              const _Float16* __restrict__ t2f,
                                              const float* __restrict__ s2,
                                              const float* __restrict__ d2,
                                              const float* __restrict__ b2,
                                              float* __restrict__ h2) {
    const int w = threadIdx.x >> 6, l = threadIdx.x & 63;
    const int v = blockIdx.x * 4 + w;
    if (v >= N_NODES) return;
    __shared__ float exw[4][64];
    __shared__ int   uw[4][64];
    const int row0 = rowptr[v], row1 = rowptr[v + 1];
    const float dvv = d2[v];
    float acc = 0.f, den = 0.f;
    for (int c0 = row0; c0 < row1; c0 += 64) {
        int nc = min(64, row1 - c0);
        if (l < nc) {
            int u = srcs[c0 + l];
            uw[w][l] = u;
            exw[w][l] = __expf(lrelu(s2[u] + dvv));
        }
        __builtin_amdgcn_wave_barrier();
        for (int j = 0; j < nc; ++j) {
            int u = uw[w][j];
            float ex = exw[w][j];
            acc += ex * (float)t2f[(size_t)u * CD + l];
            den += ex;
        }
        __builtin_amdgcn_wave_barrier();
    }
    h2[(size_t)v * CD + l] = fmaxf(acc / den + b2[l], 0.f);
}

// ---------------- head: entity sigmoid + pooling logits ----------------
__global__ __launch_bounds__(256) void k_head(const float* __restrict__ h2,
                                              const float* __restrict__ att_w,
                                              const float* __restrict__ att_b,
                                              const float* __restrict__ fc_w,
                                              const float* __restrict__ fc_b,
                                              float* __restrict__ logit,
                                              float* __restrict__ outp) {
    int wave = threadIdx.x >> 6, lane = threadIdx.x & 63;
    int v = blockIdx.x * 4 + wave;
    if (v >= N_NODES) return;
    float hv = h2[(size_t)v * CD + lane];
    float a = hv * att_w[lane];
    float f = hv * fc_w[lane];
    #pragma unroll
    for (int off = 32; off; off >>= 1) {
        a += __shfl_down(a, off, 64);
        f += __shfl_down(f, off, 64);
    }
    if (lane == 0) {
        logit[v] = a + att_b[0];
        float z = f + fc_b[0];
        outp[v] = 1.f / (1.f + __expf(-z));
    }
}

// ---------------- global softmax pooling ----------------
__global__ __launch_bounds__(256) void k_pmax(const float* __restrict__ logit,
                                              float* __restrict__ pmax) {
    __shared__ float sd[256];
    int t = threadIdx.x;
    float lm = -1e30f;
    for (int i = blockIdx.x * 256 + t; i < N_NODES; i += gridDim.x * 256)
        lm = fmaxf(lm, logit[i]);
    sd[t] = lm; __syncthreads();
    for (int s = 128; s; s >>= 1) { if (t < s) sd[t] = fmaxf(sd[t], sd[t + s]); __syncthreads(); }
    if (t == 0) pmax[blockIdx.x] = sd[0];
}

__global__ __launch_bounds__(256) void k_finmax(const float* __restrict__ pmax,
                                                float* __restrict__ gmax,
                                                float* __restrict__ gsum,
                                                float* __restrict__ gvec) {
    __shared__ float sd[256];
    int t = threadIdx.x;
    sd[t] = pmax[t];
    __syncthreads();
    for (int s = 128; s; s >>= 1) { if (t < s) sd[t] = fmaxf(sd[t], sd[t + s]); __syncthreads(); }
    if (t == 0) { *gmax = sd[0]; *gsum = 0.f; }
    if (t < 64) gvec[t] = 0.f;
}

__global__ __launch_bounds__(256) void k_pool(const float* __restrict__ h2,
                                              const float* __restrict__ logit,
                                              const float* __restrict__ gmax,
                                              float* __restrict__ gsum,
                                              float* __restrict__ gvec) {
    int wave = threadIdx.x >> 6, lane = threadIdx.x & 63;
    __shared__ float acc_s[4][64];
    __shared__ float ws_s[4];
    float m = *gmax;
    float acc = 0.f, wsum = 0.f;
    int gw = blockIdx.x * 4 + wave;
    int nw = gridDim.x * 4;
    for (int v = gw; v < N_NODES; v += nw) {
        float w = __expf(logit[v] - m);
        acc += w * h2[(size_t)v * CD + lane];
        if (lane == 0) wsum += w;
    }
    acc_s[wave][lane] = acc;
    if (lane == 0) ws_s[wave] = wsum;
    __syncthreads();
    if (threadIdx.x < 64) {
        float a = acc_s[0][threadIdx.x] + acc_s[1][threadIdx.x] +
                  acc_s[2][threadIdx.x] + acc_s[3][threadIdx.x];
        atomicAdd(&gvec[threadIdx.x], a);
    }
    if (threadIdx.x == 0)
        atomicAdd(gsum, ws_s[0] + ws_s[1] + ws_s[2] + ws_s[3]);
}

__global__ void k_writeout(const float* __restrict__ gvec,
                           const float* __restrict__ gsum,
                           float* __restrict__ outg) {
    int t = threadIdx.x;
    if (t < 64) outg[t] = gvec[t] / *gsum;
}

// ---------------- launcher ----------------
extern "C" void kernel_launch(void* const* d_in, const int* in_sizes, int n_in,
                              void* d_out, int out_size, void* d_ws, size_t ws_size,
                              hipStream_t stream) {
    const float* x    = (const float*)d_in[0];
    const int*   ei   = (const int*)d_in[1];
    const float* W1   = (const float*)d_in[2];
    const float* as1  = (const float*)d_in[3];
    const float* ad1  = (const float*)d_in[4];
    const float* b1   = (const float*)d_in[5];
    const float* W2   = (const float*)d_in[6];
    const float* as2  = (const float*)d_in[7];
    const float* ad2  = (const float*)d_in[8];
    const float* b2   = (const float*)d_in[9];
    const float* attw = (const float*)d_in[10];
    const float* attb = (const float*)d_in[11];
    const float* fcw  = (const float*)d_in[12];
    const float* fcb  = (const float*)d_in[13];
    const int* srcE = ei;
    const int* dstE = ei + N_EDGES;

    char* ws = (char*)d_ws;
    size_t off = 0;
    auto take = [&](size_t bytes) -> void* {
        void* p = ws + off;
        off += (bytes + 255) & ~(size_t)255;
        return p;
    };
    _Float16* h1f  = (_Float16*)take((size_t)N_NODES * HC * 2);
    _Float16* t2f  = (_Float16*)take((size_t)N_NODES * CD * 2);
    float* h2   = (float*)take((size_t)N_NODES * CD * 4);
    float* s1   = (float*)take((size_t)N_NODES * 4 * 4);
    float* d1   = (float*)take((size_t)N_NODES * 4 * 4);
    float* s2   = (float*)take((size_t)N_NODES * 4);
    float* d2   = (float*)take((size_t)N_NODES * 4);
    int* counts = (int*)take((size_t)N_NODES * 4);
    int* cursor = (int*)take((size_t)N_NODES * 4);
    int* rowptr = (int*)take((size_t)(N_NODES + 1) * 4);
    int* bsum   = (int*)take(64 * 4);
    int* src_sorted = (int*)take((size_t)ETOT * 4);
    _Float16* xf16 = (_Float16*)take((size_t)N_NODES * IN_DIM * 2);  // alias: out1f
    _Float16* W1T  = (_Float16*)take(256 * 256 * 2);
    _Float16* W2T  = (_Float16*)take(64 * 256 * 2);
    float* logit = (float*)take((size_t)N_NODES * 4);
    float* pmax  = (float*)take(256 * 4);
    float* gmax  = (float*)take(4);
    float* gsum  = (float*)take(4);
    float* gvec  = (float*)take(64 * 4);
    // region reuse (stream-ordered, safe): agg1 writes out1f after gemm1 consumed xf16
    _Float16* out1f = xf16;

    // CSR build
    k_init<<<(N_NODES + 255) / 256, 256, 0, stream>>>(counts, cursor);
    k_degree<<<(N_EDGES + 255) / 256, 256, 0, stream>>>(dstE, counts);
    int nb = (N_NODES + 1023) / 1024;
    k_scan_a<<<nb, 1024, 0, stream>>>(counts, rowptr, bsum);
    k_scan_b<<<1, 64, 0, stream>>>(bsum, nb);
    k_scan_c<<<(N_NODES + 255) / 256, 256, 0, stream>>>(rowptr, bsum);
    k_scatter<<<(ETOT + 255) / 256, 256, 0, stream>>>(srcE, dstE, rowptr, cursor, src_sorted);

    // fp16 conversions
    k_convx16<<<(N_NODES * IN_DIM / 4 + 255) / 256, 256, 0, stream>>>(x, xf16);
    k_convw16<<<(256 * 256 + 255) / 256, 256, 0, stream>>>(W1, W1T, HC);
    k_convw16<<<(64 * 256 + 255) / 256, 256, 0, stream>>>(W2, W2T, CD);

    // layer 1: fp16 register-fragment GEMM + fused logits -> h1f, s1, d1
    k_gemm_h<<<dim3(HC / 64, (N_NODES + 255) / 256), 256, 0, stream>>>(
        xf16, W1T, h1f, s1, d1, as1, ad1, N_NODES, HC);
    k_agg1<<<(N_NODES + 3) / 4, 256, 0, stream>>>(rowptr, src_sorted, h1f, s1, d1, b1, out1f);

    // layer 2: fp16 register-fragment GEMM + fused logits -> t2f, s2, d2
    k_gemm_h<<<dim3(CD / 64, (N_NODES + 255) / 256), 256, 0, stream>>>(
        out1f, W2T, t2f, s2, d2, as2, ad2, N_NODES, CD);
    k_agg2<<<(N_NODES + 3) / 4, 256, 0, stream>>>(rowptr, src_sorted, t2f, s2, d2, b2, h2);

    // heads
    k_head<<<(N_NODES + 3) / 4, 256, 0, stream>>>(h2, attw, attb, fcw, fcb, logit, (float*)d_out);
    k_pmax<<<256, 256, 0, stream>>>(logit, pmax);
    k_finmax<<<1, 256, 0, stream>>>(pmax, gmax, gsum, gvec);
    k_pool<<<256, 256, 0, stream>>>(h2, logit, gmax, gsum, gvec);
    k_writeout<<<1, 64, 0, stream>>>(gvec, gsum, (float*)d_out + N_NODES);
}